// Round 2
// baseline (199.202 us; speedup 1.0000x reference)
//
#include <hip/hip_runtime.h>
#include <math.h>

// ---------------------------------------------------------------------------
// QuantumGenerator: 6 dispatches (was 10).
// The 4 tiny stats kernels are gone: each qcnn layer accumulates its output's
// BN sums via device-scope global atomicAdd (<=32 atomics/block), and the
// CONSUMER kernel finalizes mean/var -> scale/shift inline per thread.
// build_V also zeroes the stat accumulators; kernel boundaries provide all
// memory-visibility guarantees (no grid sync, no co-residency assumptions).
// Per channel only the top-left 4x4 of the 8x8 unitary matters.
// ---------------------------------------------------------------------------

#define NB 1024   // blocks for qcnn kernels (x256 threads, x4 iters = 1M patches)

__global__ __launch_bounds__(256) void build_V_kernel(
    const float* __restrict__ w1, const float* __restrict__ w2,
    const float* __restrict__ w3, const float* __restrict__ w4,
    float* __restrict__ V, float* __restrict__ stats /*176 floats*/)
{
    int t = blockIdx.x * blockDim.x + threadIdx.x;
    if (t < 176) stats[t] = 0.0f;     // zero all BN accumulators for this run
    if (t >= 340) return;
    const float* w; float* vout;
    if (t < 256)      { w = w1 + t*18;        vout = V + t*16; }
    else if (t < 320) { w = w2 + (t-256)*18;  vout = V + 4096 + (t-256)*16; }
    else if (t < 336) { w = w3 + (t-320)*18;  vout = V + 5120 + (t-320)*16; }
    else              { w = w4 + (t-336)*18;  vout = V + 5376 + (t-336)*16; }
    // CNOT ring: new[perm[r]] = old[r]
    const int perm[8] = {0,5,7,2,3,6,4,1};
    float U[8][8];
    #pragma unroll
    for (int i=0;i<8;i++)
        #pragma unroll
        for (int j=0;j<8;j++) U[i][j] = (i==j) ? 1.0f : 0.0f;
    for (int l=0;l<6;l++){
        float c0 = cosf(0.5f*w[l*3+0]), s0 = sinf(0.5f*w[l*3+0]);  // qubit 2 (MSB)
        float c1 = cosf(0.5f*w[l*3+1]), s1 = sinf(0.5f*w[l*3+1]);  // qubit 1
        float c2 = cosf(0.5f*w[l*3+2]), s2 = sinf(0.5f*w[l*3+2]);  // qubit 0 (LSB)
        #pragma unroll
        for (int col=0; col<8; col++){
            float v[8];
            #pragma unroll
            for (int r=0;r<8;r++) v[r] = U[r][col];
            // Ry(w2) on bit0
            #pragma unroll
            for (int b=0;b<8;b+=2){ float x=v[b], y=v[b+1]; v[b]=c2*x-s2*y; v[b+1]=s2*x+c2*y; }
            // Ry(w1) on bit1
            #pragma unroll
            for (int g=0;g<8;g+=4)
                #pragma unroll
                for (int i=0;i<2;i++){ int a=g+i, b=g+i+2; float x=v[a], y=v[b]; v[a]=c1*x-s1*y; v[b]=s1*x+c1*y; }
            // Ry(w0) on bit2
            #pragma unroll
            for (int i=0;i<4;i++){ float x=v[i], y=v[i+4]; v[i]=c0*x-s0*y; v[i+4]=s0*x+c0*y; }
            #pragma unroll
            for (int r=0;r<8;r++) U[perm[r]][col] = v[r];
        }
    }
    #pragma unroll
    for (int j=0;j<4;j++)
        #pragma unroll
        for (int k=0;k<4;k++) vout[j*4+k] = U[j][k];
}

// One thread = one (channel, patch) slot, iterated over 4 batch indices.
// r/c/p invariant across iterations -> V fragment + BN scale/shift hoisted.
template<int C, int H, int W, bool BN>
__global__ __launch_bounds__(256) void qcnn_kernel(
    const float* __restrict__ x, const float* __restrict__ V,
    const float* __restrict__ isum, const float* __restrict__ issq,
    const float* __restrict__ gamma, const float* __restrict__ beta,
    float invNin,
    float* __restrict__ out, float* __restrict__ osum, float* __restrict__ ossq)
{
    constexpr int HW  = H*W;
    constexpr int P   = HW/4;                 // patches per channel: 4,16,64,256
    constexpr int OW  = W/2;
    constexpr int LP  = (P==4)?2:(P==16)?4:(P==64)?6:8;
    constexpr int LOW = (OW==2)?1:(OW==4)?2:(OW==8)?3:4;
    constexpr int CPB = 256/P;                // input channels per block r-range
    constexpr int OCB = (CPB/4) < 1 ? 1 : (CPB/4);  // BN bins per block
    constexpr int G   = (4*P < 64) ? 4*P : 64;      // lanes sharing one BN bin

    __shared__ float sBin[2*OCB];
    if (threadIdx.x < 2*OCB) sBin[threadIdx.x] = 0.0f;
    __syncthreads();

    const int r   = ((blockIdx.x & 3) << 8) + threadIdx.x;   // per-batch flat idx
    const int c   = r >> LP;
    const int p   = r & (P-1);
    const int oh  = p >> LOW;
    const int ow  = p & (OW-1);
    const int oc0 = ((blockIdx.x & 3) << 8) >> (LP+2);
    const int ocl = (r >> (LP+2)) - oc0;
    const int xoff = c*HW + (oh*2)*W + (ow*2);
    const int ooff = c*HW + (p<<2);

    float sc = 0.0f, sh = 0.0f;
    if constexpr (BN){
        // inline BN finalize for the INPUT (replaces a stats dispatch)
        float s = isum[c], q = issq[c];
        float mean = s * invNin;
        float var  = q * invNin - mean*mean;
        float rinv = 1.0f / sqrtf(var + 1e-5f);
        sc = gamma[c] * rinv;
        sh = beta[c] - mean * sc;
    }
    const float4* Vc = reinterpret_cast<const float4*>(V + c*16);
    const float4 v0 = Vc[0], v1 = Vc[1], v2 = Vc[2], v3 = Vc[3];

    #pragma unroll
    for (int it=0; it<4; ++it){
        const int b = (it<<8) + (blockIdx.x>>2);
        const float* xb = x + ((size_t)b<<12) + xoff;
        float2 t0 = *reinterpret_cast<const float2*>(xb);
        float2 t1 = *reinterpret_cast<const float2*>(xb + W);
        float x0=t0.x, x1=t0.y, x2=t1.x, x3=t1.y;
        if constexpr (BN){
            x0 = fmaxf(x0*sc+sh, 0.0f);
            x1 = fmaxf(x1*sc+sh, 0.0f);
            x2 = fmaxf(x2*sc+sh, 0.0f);
            x3 = fmaxf(x3*sc+sh, 0.0f);
        }
        float nrm = sqrtf(x0*x0 + x1*x1 + x2*x2 + x3*x3);
        float inv = 1.0f / fmaxf(nrm, 1e-9f);
        float a0=x0*inv, a1=x1*inv, a2=x2*inv, a3=x3*inv;
        float q0 = v0.x*a0 + v0.y*a1 + v0.z*a2 + v0.w*a3;
        float q1 = v1.x*a0 + v1.y*a1 + v1.z*a2 + v1.w*a3;
        float q2 = v2.x*a0 + v2.y*a1 + v2.z*a2 + v2.w*a3;
        float q3 = v3.x*a0 + v3.y*a1 + v3.z*a2 + v3.w*a3;
        q0*=q0; q1*=q1; q2*=q2; q3*=q3;
        float s = q0+q1+q2+q3;
        float dinv = 1.0f / fmaxf(s, 1e-9f);
        float d0=q0*dinv, d1=q1*dinv, d2=q2*dinv, d3=q3*dinv;
        *reinterpret_cast<float4*>(out + ((size_t)b<<12) + ooff) =
            make_float4(d0,d1,d2,d3);
        // BN stats of the OUTPUT (channel = c>>2)
        float ls  = d0+d1+d2+d3;
        float lss = d0*d0 + d1*d1 + d2*d2 + d3*d3;
        #pragma unroll
        for (int off=1; off<G; off<<=1){ ls += __shfl_xor(ls, off); lss += __shfl_xor(lss, off); }
        if ((threadIdx.x & (G-1)) == 0){
            atomicAdd(&sBin[ocl], ls);
            atomicAdd(&sBin[OCB + ocl], lss);
        }
    }
    __syncthreads();
    if (threadIdx.x < OCB){
        atomicAdd(&osum[oc0 + threadIdx.x], sBin[threadIdx.x]);
        atomicAdd(&ossq[oc0 + threadIdx.x], sBin[OCB + threadIdx.x]);
    }
}

__global__ __launch_bounds__(256) void final_kernel(
    const float* __restrict__ s4, const float* __restrict__ gfs,
    const float* __restrict__ gfq, const float* __restrict__ gammaf,
    const float* __restrict__ betaf,
    float* __restrict__ out_tanh, float* __restrict__ out_bn)
{
    float s = gfs[0], q = gfq[0];
    float mean = s * (1.0f/4194304.0f);
    float var  = q * (1.0f/4194304.0f) - mean*mean;
    float rinv = 1.0f / sqrtf(var + 1e-5f);
    float sc = gammaf[0]*rinv;
    float sh = betaf[0] - mean*sc;
    int i = blockIdx.x*blockDim.x + threadIdx.x;   // 1M threads over float4s
    float4 v = reinterpret_cast<const float4*>(s4)[i];
    float4 bn = make_float4(v.x*sc+sh, v.y*sc+sh, v.z*sc+sh, v.w*sc+sh);
    reinterpret_cast<float4*>(out_bn)[i] = bn;
    reinterpret_cast<float4*>(out_tanh)[i] =
        make_float4(tanhf(bn.x), tanhf(bn.y), tanhf(bn.z), tanhf(bn.w));
}

extern "C" void kernel_launch(void* const* d_in, const int* in_sizes, int n_in,
                              void* d_out, int out_size, void* d_ws, size_t ws_size,
                              hipStream_t stream)
{
    const float* z      = (const float*)d_in[0];
    const float* w1     = (const float*)d_in[1];
    const float* w2     = (const float*)d_in[2];
    const float* w3     = (const float*)d_in[3];
    const float* w4     = (const float*)d_in[4];
    const float* gamma2 = (const float*)d_in[5];
    const float* beta2  = (const float*)d_in[6];
    const float* gamma3 = (const float*)d_in[7];
    const float* beta3  = (const float*)d_in[8];
    const float* gamma4 = (const float*)d_in[9];
    const float* beta4  = (const float*)d_in[10];
    const float* gammaf = (const float*)d_in[11];
    const float* betaf  = (const float*)d_in[12];
    float* out = (float*)d_out;
    float* ws  = (float*)d_ws;

    // workspace layout (floats)
    float* V    = ws;                                     // 5440
    float* g2s  = ws + 6144;  float* g2q = ws + 6208;     // 64 + 64
    float* g3s  = ws + 6272;  float* g3q = ws + 6288;     // 16 + 16
    float* g4s  = ws + 6304;  float* g4q = ws + 6308;     // 4 + 4
    float* gfs  = ws + 6312;  float* gfq = ws + 6313;     // 1 + 1
    float* bufA = ws + 65536;                 // 4M floats (s1, then s3)
    float* bufB = bufA + 4194304;             // 4M floats (s2)
    float* s4   = out + 4194304;              // output slot 1
    float* s4bn = out + 8388608;              // output slot 2

    build_V_kernel<<<2, 256, 0, stream>>>(w1, w2, w3, w4, V, ws + 6144);

    // L1: z (1024,256,4,4) -> s1; output stats over 64 ch (N=65536/ch)
    qcnn_kernel<256,4,4,false><<<NB, 256, 0, stream>>>(
        z, V, nullptr, nullptr, nullptr, nullptr, 0.0f, bufA, g2s, g2q);

    // L2: relu(bn(s1)) -> s2; output stats over 16 ch (N=262144/ch)
    qcnn_kernel<64,8,8,true><<<NB, 256, 0, stream>>>(
        bufA, V+4096, g2s, g2q, gamma2, beta2, 1.0f/65536.0f, bufB, g3s, g3q);

    // L3: -> s3; output stats over 4 ch (N=1048576/ch)
    qcnn_kernel<16,16,16,true><<<NB, 256, 0, stream>>>(
        bufB, V+5120, g3s, g3q, gamma3, beta3, 1.0f/262144.0f, bufA, g4s, g4q);

    // L4: -> s4 (out slot 1); output stats over 1 ch (N=4194304)
    qcnn_kernel<4,32,32,true><<<NB, 256, 0, stream>>>(
        bufA, V+5376, g4s, g4q, gamma4, beta4, 1.0f/1048576.0f, s4, gfs, gfq);

    // final: s4_bn -> out slot 2, tanh(s4_bn) -> out slot 0
    final_kernel<<<4096, 256, 0, stream>>>(s4, gfs, gfq, gammaf, betaf, out, s4bn);
}

// Round 3
// 156.486 us; speedup vs baseline: 1.2730x; 1.2730x over previous
//
#include <hip/hip_runtime.h>
#include <math.h>

// ---------------------------------------------------------------------------
// QuantumGenerator: 6 dispatches.
// BN stats flow producer -> consumer with NO stats dispatch and NO hot atomics:
//   producer block: wave shuffle-reduce -> LDS bins -> ONE atomicAdd per
//     channel-bin into partial[ch][(bid>>2)&31]  (max 8-32 adds per address,
//     spread across cache lines -- avoids the cross-XCD same-address
//     serialization that cost ~50us in the previous version)
//   consumer block prologue: <=32 threads reduce the 32 slots of the channels
//     this block consumes (8x float4 loads each, L2 broadcast) -> LDS ->
//     every thread computes scale/shift inline.
// Per channel only the top-left 4x4 of the 8x8 unitary matters.
// ---------------------------------------------------------------------------

#define NB 1024   // blocks for qcnn kernels (x256 threads, x4 iters = 1M patches)
#define NSLOT 32  // partial slots per BN channel

__global__ __launch_bounds__(256) void build_V_kernel(
    const float* __restrict__ w1, const float* __restrict__ w2,
    const float* __restrict__ w3, const float* __restrict__ w4,
    float* __restrict__ V, float* __restrict__ stats /*5440 floats*/)
{
    int t = blockIdx.x * blockDim.x + threadIdx.x;
    for (int i = t; i < 5440; i += 512) stats[i] = 0.0f;   // zero BN partials
    if (t >= 340) return;
    const float* w; float* vout;
    if (t < 256)      { w = w1 + t*18;        vout = V + t*16; }
    else if (t < 320) { w = w2 + (t-256)*18;  vout = V + 4096 + (t-256)*16; }
    else if (t < 336) { w = w3 + (t-320)*18;  vout = V + 5120 + (t-320)*16; }
    else              { w = w4 + (t-336)*18;  vout = V + 5376 + (t-336)*16; }
    // CNOT ring: new[perm[r]] = old[r]
    const int perm[8] = {0,5,7,2,3,6,4,1};
    float U[8][8];
    #pragma unroll
    for (int i=0;i<8;i++)
        #pragma unroll
        for (int j=0;j<8;j++) U[i][j] = (i==j) ? 1.0f : 0.0f;
    for (int l=0;l<6;l++){
        float c0 = cosf(0.5f*w[l*3+0]), s0 = sinf(0.5f*w[l*3+0]);  // qubit 2 (MSB)
        float c1 = cosf(0.5f*w[l*3+1]), s1 = sinf(0.5f*w[l*3+1]);  // qubit 1
        float c2 = cosf(0.5f*w[l*3+2]), s2 = sinf(0.5f*w[l*3+2]);  // qubit 0 (LSB)
        #pragma unroll
        for (int col=0; col<8; col++){
            float v[8];
            #pragma unroll
            for (int r=0;r<8;r++) v[r] = U[r][col];
            // Ry(w2) on bit0
            #pragma unroll
            for (int b=0;b<8;b+=2){ float x=v[b], y=v[b+1]; v[b]=c2*x-s2*y; v[b+1]=s2*x+c2*y; }
            // Ry(w1) on bit1
            #pragma unroll
            for (int g=0;g<8;g+=4)
                #pragma unroll
                for (int i=0;i<2;i++){ int a=g+i, b=g+i+2; float x=v[a], y=v[b]; v[a]=c1*x-s1*y; v[b]=s1*x+c1*y; }
            // Ry(w0) on bit2
            #pragma unroll
            for (int i=0;i<4;i++){ float x=v[i], y=v[i+4]; v[i]=c0*x-s0*y; v[i+4]=s0*x+c0*y; }
            #pragma unroll
            for (int r=0;r<8;r++) U[perm[r]][col] = v[r];
        }
    }
    #pragma unroll
    for (int j=0;j<4;j++)
        #pragma unroll
        for (int k=0;k<4;k++) vout[j*4+k] = U[j][k];
}

// One thread = one (channel, patch) slot, iterated over 4 batch indices.
// r/c/p invariant across iterations -> V fragment + BN scale/shift hoisted.
template<int C, int H, int W, bool BN>
__global__ __launch_bounds__(256) void qcnn_kernel(
    const float* __restrict__ x, const float* __restrict__ V,
    const float* __restrict__ isum, const float* __restrict__ issq,
    const float* __restrict__ gamma, const float* __restrict__ beta,
    float invNin,
    float* __restrict__ out, float* __restrict__ osum, float* __restrict__ ossq)
{
    constexpr int HW  = H*W;
    constexpr int P   = HW/4;                 // patches per channel: 4,16,64,256
    constexpr int OW  = W/2;
    constexpr int LP  = (P==4)?2:(P==16)?4:(P==64)?6:8;
    constexpr int LOW = (OW==2)?1:(OW==4)?2:(OW==8)?3:4;
    constexpr int CPB = 256/P;                // input channels per block
    constexpr int OCB = (CPB/4) < 1 ? 1 : (CPB/4);  // output BN bins per block
    constexpr int G   = (4*P < 64) ? 4*P : 64;      // lanes sharing one BN bin

    __shared__ float sBin[2*OCB];
    __shared__ float sRed[2*CPB];

    if (threadIdx.x < 2*OCB) sBin[threadIdx.x] = 0.0f;
    if constexpr (BN){
        // consumer prologue: reduce the 32 partial slots for this block's
        // CPB input channels (<=32 threads, 8 float4 loads each)
        if (threadIdx.x < 2*CPB){
            const int cl  = threadIdx.x & (CPB-1);
            const int arr = threadIdx.x / CPB;
            const int c0  = (blockIdx.x & 3) * CPB;
            const float4* p4 = reinterpret_cast<const float4*>(
                (arr ? issq : isum) + (c0+cl)*NSLOT);
            float s = 0.0f;
            #pragma unroll
            for (int i=0;i<NSLOT/4;i++){ float4 v = p4[i]; s += v.x+v.y+v.z+v.w; }
            sRed[threadIdx.x] = s;
        }
    }
    __syncthreads();

    const int r   = ((blockIdx.x & 3) << 8) + threadIdx.x;   // per-batch flat idx
    const int c   = r >> LP;
    const int p   = r & (P-1);
    const int oh  = p >> LOW;
    const int ow  = p & (OW-1);
    const int oc0 = ((blockIdx.x & 3) << 8) >> (LP+2);
    const int ocl = (r >> (LP+2)) - oc0;
    const int xoff = c*HW + (oh*2)*W + (ow*2);
    const int ooff = c*HW + (p<<2);

    float sc = 0.0f, sh = 0.0f;
    if constexpr (BN){
        const int cl = c - (blockIdx.x & 3) * CPB;
        float s = sRed[cl], q = sRed[CPB+cl];
        float mean = s * invNin;
        float var  = q * invNin - mean*mean;
        float rinv = 1.0f / sqrtf(var + 1e-5f);
        sc = gamma[c] * rinv;
        sh = beta[c] - mean * sc;
    }
    const float4* Vc = reinterpret_cast<const float4*>(V + c*16);
    const float4 v0 = Vc[0], v1 = Vc[1], v2 = Vc[2], v3 = Vc[3];

    #pragma unroll
    for (int it=0; it<4; ++it){
        const int b = (it<<8) + (blockIdx.x>>2);
        const float* xb = x + ((size_t)b<<12) + xoff;
        float2 t0 = *reinterpret_cast<const float2*>(xb);
        float2 t1 = *reinterpret_cast<const float2*>(xb + W);
        float x0=t0.x, x1=t0.y, x2=t1.x, x3=t1.y;
        if constexpr (BN){
            x0 = fmaxf(x0*sc+sh, 0.0f);
            x1 = fmaxf(x1*sc+sh, 0.0f);
            x2 = fmaxf(x2*sc+sh, 0.0f);
            x3 = fmaxf(x3*sc+sh, 0.0f);
        }
        float nrm = sqrtf(x0*x0 + x1*x1 + x2*x2 + x3*x3);
        float inv = 1.0f / fmaxf(nrm, 1e-9f);
        float a0=x0*inv, a1=x1*inv, a2=x2*inv, a3=x3*inv;
        float q0 = v0.x*a0 + v0.y*a1 + v0.z*a2 + v0.w*a3;
        float q1 = v1.x*a0 + v1.y*a1 + v1.z*a2 + v1.w*a3;
        float q2 = v2.x*a0 + v2.y*a1 + v2.z*a2 + v2.w*a3;
        float q3 = v3.x*a0 + v3.y*a1 + v3.z*a2 + v3.w*a3;
        q0*=q0; q1*=q1; q2*=q2; q3*=q3;
        float s = q0+q1+q2+q3;
        float dinv = 1.0f / fmaxf(s, 1e-9f);
        float d0=q0*dinv, d1=q1*dinv, d2=q2*dinv, d3=q3*dinv;
        *reinterpret_cast<float4*>(out + ((size_t)b<<12) + ooff) =
            make_float4(d0,d1,d2,d3);
        // BN stats of the OUTPUT (channel = c>>2)
        float ls  = d0+d1+d2+d3;
        float lss = d0*d0 + d1*d1 + d2*d2 + d3*d3;
        #pragma unroll
        for (int off=1; off<G; off<<=1){ ls += __shfl_xor(ls, off); lss += __shfl_xor(lss, off); }
        if ((threadIdx.x & (G-1)) == 0){
            atomicAdd(&sBin[ocl], ls);
            atomicAdd(&sBin[OCB + ocl], lss);
        }
    }
    __syncthreads();
    if (threadIdx.x < OCB){
        const int slot = (blockIdx.x >> 2) & (NSLOT-1);   // 8-32 adds per address
        atomicAdd(&osum[(oc0+threadIdx.x)*NSLOT + slot], sBin[threadIdx.x]);
        atomicAdd(&ossq[(oc0+threadIdx.x)*NSLOT + slot], sBin[OCB+threadIdx.x]);
    }
}

__global__ __launch_bounds__(256) void final_kernel(
    const float* __restrict__ s4, const float* __restrict__ gfs,
    const float* __restrict__ gfq, const float* __restrict__ gammaf,
    const float* __restrict__ betaf,
    float* __restrict__ out_tanh, float* __restrict__ out_bn)
{
    __shared__ float sSS[2];
    if (threadIdx.x < 2){
        const float4* p4 = reinterpret_cast<const float4*>(threadIdx.x ? gfq : gfs);
        float s = 0.0f;
        #pragma unroll
        for (int i=0;i<NSLOT/4;i++){ float4 v = p4[i]; s += v.x+v.y+v.z+v.w; }
        sSS[threadIdx.x] = s;
    }
    __syncthreads();
    float mean = sSS[0] * (1.0f/4194304.0f);
    float var  = sSS[1] * (1.0f/4194304.0f) - mean*mean;
    float rinv = 1.0f / sqrtf(var + 1e-5f);
    float sc = gammaf[0]*rinv;
    float sh = betaf[0] - mean*sc;
    int i = blockIdx.x*blockDim.x + threadIdx.x;   // 1M threads over float4s
    float4 v = reinterpret_cast<const float4*>(s4)[i];
    float4 bn = make_float4(v.x*sc+sh, v.y*sc+sh, v.z*sc+sh, v.w*sc+sh);
    reinterpret_cast<float4*>(out_bn)[i] = bn;
    reinterpret_cast<float4*>(out_tanh)[i] =
        make_float4(tanhf(bn.x), tanhf(bn.y), tanhf(bn.z), tanhf(bn.w));
}

extern "C" void kernel_launch(void* const* d_in, const int* in_sizes, int n_in,
                              void* d_out, int out_size, void* d_ws, size_t ws_size,
                              hipStream_t stream)
{
    const float* z      = (const float*)d_in[0];
    const float* w1     = (const float*)d_in[1];
    const float* w2     = (const float*)d_in[2];
    const float* w3     = (const float*)d_in[3];
    const float* w4     = (const float*)d_in[4];
    const float* gamma2 = (const float*)d_in[5];
    const float* beta2  = (const float*)d_in[6];
    const float* gamma3 = (const float*)d_in[7];
    const float* beta3  = (const float*)d_in[8];
    const float* gamma4 = (const float*)d_in[9];
    const float* beta4  = (const float*)d_in[10];
    const float* gammaf = (const float*)d_in[11];
    const float* betaf  = (const float*)d_in[12];
    float* out = (float*)d_out;
    float* ws  = (float*)d_ws;

    // workspace layout (floats); all partial arrays are [ch][NSLOT]
    float* V    = ws;                                   // 5440
    float* g2s  = ws + 6144;   float* g2q = ws + 8192;  // 64*32 each
    float* g3s  = ws + 10240;  float* g3q = ws + 10752; // 16*32 each
    float* g4s  = ws + 11264;  float* g4q = ws + 11392; // 4*32 each
    float* gfs  = ws + 11520;  float* gfq = ws + 11552; // 1*32 each
    float* bufA = ws + 65536;                 // 4M floats (s1, then s3)
    float* bufB = bufA + 4194304;             // 4M floats (s2)
    float* s4   = out + 4194304;              // output slot 1
    float* s4bn = out + 8388608;              // output slot 2

    build_V_kernel<<<2, 256, 0, stream>>>(w1, w2, w3, w4, V, ws + 6144);

    // L1: z (1024,256,4,4) -> s1; output stats over 64 ch (N=65536/ch)
    qcnn_kernel<256,4,4,false><<<NB, 256, 0, stream>>>(
        z, V, nullptr, nullptr, nullptr, nullptr, 0.0f, bufA, g2s, g2q);

    // L2: relu(bn(s1)) -> s2; output stats over 16 ch (N=262144/ch)
    qcnn_kernel<64,8,8,true><<<NB, 256, 0, stream>>>(
        bufA, V+4096, g2s, g2q, gamma2, beta2, 1.0f/65536.0f, bufB, g3s, g3q);

    // L3: -> s3; output stats over 4 ch (N=1048576/ch)
    qcnn_kernel<16,16,16,true><<<NB, 256, 0, stream>>>(
        bufB, V+5120, g3s, g3q, gamma3, beta3, 1.0f/262144.0f, bufA, g4s, g4q);

    // L4: -> s4 (out slot 1); output stats over 1 ch (N=4194304)
    qcnn_kernel<4,32,32,true><<<NB, 256, 0, stream>>>(
        bufA, V+5376, g4s, g4q, gamma4, beta4, 1.0f/1048576.0f, s4, gfs, gfq);

    // final: s4_bn -> out slot 2, tanh(s4_bn) -> out slot 0
    final_kernel<<<4096, 256, 0, stream>>>(s4, gfs, gfq, gammaf, betaf, out, s4bn);
}